// Round 1
// baseline (132.483 us; speedup 1.0000x reference)
//
#include <hip/hip_runtime.h>
#include <stdint.h>

typedef unsigned short u16;
typedef __bf16 v8bf __attribute__((ext_vector_type(8)));
typedef float  v4f  __attribute__((ext_vector_type(4)));

#define NPIX   32768
#define DIM    256
#define KCODE  1024
#define HW     1024

// workspace layout (bytes)
#define WS_XB    0                         // bf16 [NPIX][DIM]   = 16 MB
#define WS_EB    16777216                  // bf16 [KCODE][DIM]  = 512 KB
#define WS_NORM  (WS_EB + 524288)          // f32  [KCODE]       = 4 KB
#define WS_INDS  (WS_NORM + 4096)          // i32  [NPIX]        = 128 KB
#define WS_ACC   (WS_INDS + 131072)        // f32  [1]

// ---------------------------------------------------------------- kernel A
__global__ __launch_bounds__(256) void k_prep(const float* __restrict__ E,
                                              u16* __restrict__ Eb,
                                              float* __restrict__ norms,
                                              float* __restrict__ acc) {
  const int c = blockIdx.x, t = threadIdx.x;
  const float v = E[c * DIM + t];
  const __bf16 h = (__bf16)v;
  Eb[c * DIM + t] = __builtin_bit_cast(unsigned short, h);
  float s = v * v;
  #pragma unroll
  for (int m = 32; m; m >>= 1) s += __shfl_xor(s, m, 64);
  __shared__ float wsum[4];
  if ((t & 63) == 0) wsum[t >> 6] = s;
  __syncthreads();
  if (t == 0) {
    norms[c] = wsum[0] + wsum[1] + wsum[2] + wsum[3];
    if (c == 0) *acc = 0.f;
  }
}

// ---------------------------------------------------------------- kernel A2
// latents [B][D][HW] f32 -> Xb [N=B*HW][D] bf16 (tiled 64x64 transpose)
__global__ __launch_bounds__(256) void k_transpose(const float* __restrict__ latents,
                                                   u16* __restrict__ Xb) {
  __shared__ float tile[64][65];
  const int t   = threadIdx.x;
  const int bid = blockIdx.x;          // 32 b * 4 dt * 16 ht = 2048
  const int b   = bid >> 6;
  const int dt  = (bid >> 4) & 3;
  const int ht  = bid & 15;
  const int d0  = dt << 6, hw0 = ht << 6;
  const int c   = t & 63;
  const int r4  = t >> 6;              // 0..3
  const float* lp = latents + (((size_t)(b * DIM + d0)) << 10) + hw0;
  #pragma unroll
  for (int dd = 0; dd < 64; dd += 4)
    tile[dd + r4][c] = lp[((size_t)(dd + r4) << 10) + c];
  __syncthreads();
  const int dl  = (t & 31) * 2;
  const int hwr = t >> 5;              // 0..7
  u16* xp = Xb + ((size_t)(b * HW + hw0)) * DIM + d0;
  #pragma unroll
  for (int hh = 0; hh < 64; hh += 8) {
    const int hw = hh + hwr;
    const __bf16 h0 = (__bf16)tile[dl][hw];
    const __bf16 h1 = (__bf16)tile[dl + 1][hw];
    ushort2 u;
    u.x = __builtin_bit_cast(unsigned short, h0);
    u.y = __builtin_bit_cast(unsigned short, h1);
    *(ushort2*)(xp + (size_t)hw * DIM + dl) = u;
  }
}

// ---------------------------------------------------------------- kernel B
#define NT 128           // pixels per block (4 waves x 32)
#define CT 64            // codes per c-iter
#define CITERS (KCODE / CT)

__device__ __forceinline__ void gld_lds16(const void* src, void* dst_wave_base) {
  const unsigned int ldsoff =
      __builtin_amdgcn_readfirstlane((unsigned int)(uintptr_t)dst_wave_base);
  __builtin_amdgcn_global_load_lds(
      (const __attribute__((address_space(1))) void*)(uintptr_t)src,
      (__attribute__((address_space(3))) void*)(uintptr_t)ldsoff,
      16, 0, 0);
}

// stage 64x256 bf16 E tile (32KB) into LDS, source pre-swizzled so a
// swizzled ds_read_b128 is bank-conflict-free (T2 both-sides-or-neither)
__device__ __forceinline__ void stage_tile(const u16* __restrict__ Eb, u16* tile,
                                           int c0, int t) {
  const int wv = t >> 6;
  #pragma unroll
  for (int r = 0; r < 8; ++r) {
    const int s  = r * 256 + t;              // 16B slot 0..2047
    const int sp = s ^ ((s >> 5) & 7);       // inverse swizzle on the source
    const char* src = (const char*)(Eb + (size_t)(c0 + (s >> 5)) * DIM)
                      + ((sp & 31) << 4);
    char* dst = (char*)tile + ((r * 256 + wv * 64) << 4);
    gld_lds16(src, dst);
  }
}

__global__ __launch_bounds__(256) void k_argmin(const u16* __restrict__ Xb,
                                                const u16* __restrict__ Eb,
                                                const float* __restrict__ norms,
                                                int* __restrict__ inds) {
  __shared__ u16 etile[2][CT * DIM];     // 2 x 32 KB, double buffered
  __shared__ float nlds[KCODE];          // 4 KB

  const int t    = threadIdx.x;
  const int lane = t & 63;
  const int wv   = t >> 6;               // 0..3
  const int l15  = lane & 15;
  const int l4   = lane >> 4;            // 0..3
  const int n0   = blockIdx.x * NT;

  #pragma unroll
  for (int r = 0; r < 4; ++r) nlds[t + r * 256] = norms[t + r * 256];

  // A fragments: 2 row-frags x 8 k-steps, each lane 16B contiguous
  v8bf a[2][8];
  #pragma unroll
  for (int rf = 0; rf < 2; ++rf) {
    const size_t row = (size_t)(n0 + wv * 32 + rf * 16 + l15);
    const u16* xp = Xb + row * DIM + l4 * 8;
    #pragma unroll
    for (int kk = 0; kk < 8; ++kk)
      a[rf][kk] = *(const v8bf*)(xp + kk * 32);
  }

  stage_tile(Eb, &etile[0][0], 0, t);

  float minv[2][4];
  int   mini[2][4];
  #pragma unroll
  for (int rf = 0; rf < 2; ++rf)
    #pragma unroll
    for (int i = 0; i < 4; ++i) { minv[rf][i] = 3.4e38f; mini[rf][i] = 0; }

  __syncthreads();   // drains vmcnt(0): tile 0 staged

  for (int ci = 0; ci < CITERS; ++ci) {
    const u16* buf = &etile[ci & 1][0];
    if (ci + 1 < CITERS) stage_tile(Eb, &etile[(ci + 1) & 1][0], (ci + 1) * CT, t);
    const int c0 = ci * CT;
    #pragma unroll
    for (int cf = 0; cf < 4; ++cf) {
      const int cl    = cf * 16 + l15;
      const int abase = cl * 512 + l4 * 16;
      const int sw    = (cl & 7) << 4;
      v8bf bfr[8];
      #pragma unroll
      for (int kk = 0; kk < 8; ++kk)
        bfr[kk] = *(const v8bf*)((const char*)buf + ((abase + kk * 64) ^ sw));
      v4f acc0 = {0.f, 0.f, 0.f, 0.f}, acc1 = {0.f, 0.f, 0.f, 0.f};
      #pragma unroll
      for (int kk = 0; kk < 8; ++kk) {
        acc0 = __builtin_amdgcn_mfma_f32_16x16x32_bf16(a[0][kk], bfr[kk], acc0, 0, 0, 0);
        acc1 = __builtin_amdgcn_mfma_f32_16x16x32_bf16(a[1][kk], bfr[kk], acc1, 0, 0, 0);
      }
      const int   c   = c0 + cl;
      const float nrm = nlds[c];
      #pragma unroll
      for (int i = 0; i < 4; ++i) {
        const float d0 = nrm - 2.f * acc0[i];
        if (d0 < minv[0][i]) { minv[0][i] = d0; mini[0][i] = c; }
        const float d1 = nrm - 2.f * acc1[i];
        if (d1 < minv[1][i]) { minv[1][i] = d1; mini[1][i] = c; }
      }
    }
    __syncthreads();  // next tile staged + safe to overwrite read buffer
  }

  // per-row argmin: butterfly across the 16 lanes sharing a row
  #pragma unroll
  for (int rf = 0; rf < 2; ++rf)
    #pragma unroll
    for (int i = 0; i < 4; ++i) {
      float v  = minv[rf][i];
      int   ix = mini[rf][i];
      #pragma unroll
      for (int m = 1; m < 16; m <<= 1) {
        const float ov = __shfl_xor(v, m, 64);
        const int   oi = __shfl_xor(ix, m, 64);
        if (ov < v || (ov == v && oi < ix)) { v = ov; ix = oi; }
      }
      if (l15 == 0) inds[n0 + wv * 32 + rf * 16 + l4 * 4 + i] = ix;
    }
}

// ---------------------------------------------------------------- kernel C
__global__ __launch_bounds__(256) void k_gather(const float* __restrict__ latents,
                                                const float* __restrict__ E,
                                                const int* __restrict__ inds,
                                                float* __restrict__ out,
                                                float* __restrict__ acc) {
  __shared__ float er[64][257];
  __shared__ int   il[64];
  __shared__ float wsum[4];
  const int t    = threadIdx.x;
  const int bid  = blockIdx.x;           // 32 b * 16 hwt = 512
  const int b    = bid >> 4;
  const int hw0  = (bid & 15) << 6;
  const int lane = t & 63, wv = t >> 6;
  if (t < 64) il[t] = inds[b * HW + hw0 + t];
  __syncthreads();
  for (int p = wv; p < 64; p += 4) {
    const float* ep = E + (size_t)il[p] * DIM;
    #pragma unroll
    for (int j = 0; j < 4; ++j)
      er[p][lane + 64 * j] = ep[lane + 64 * j];
  }
  __syncthreads();
  float lsum = 0.f;
  const int hw = lane;
  const float* lp = latents + (((size_t)b * DIM) << 10) + hw0 + hw;
  float*       op = out     + (((size_t)b * DIM) << 10) + hw0 + hw;
  #pragma unroll 4
  for (int db = 0; db < DIM; db += 4) {
    const int d   = db + wv;
    const float x = lp[(size_t)d << 10];
    const float q = er[hw][d];
    op[(size_t)d << 10] = q;
    const float df = q - x;
    lsum = fmaf(df, df, lsum);
  }
  #pragma unroll
  for (int m = 32; m; m >>= 1) lsum += __shfl_xor(lsum, m, 64);
  if (lane == 0) wsum[wv] = lsum;
  __syncthreads();
  if (t == 0) atomicAdd(acc, wsum[0] + wsum[1] + wsum[2] + wsum[3]);
}

// ---------------------------------------------------------------- kernel D
__global__ void k_final(const float* __restrict__ acc, float* __restrict__ loss) {
  // vq_loss = (BETA + 1) * mean = 1.25 * sum / (N*D)
  *loss = *acc * (1.25f / 8388608.f);
}

// ----------------------------------------------------------------
extern "C" void kernel_launch(void* const* d_in, const int* in_sizes, int n_in,
                              void* d_out, int out_size, void* d_ws, size_t ws_size,
                              hipStream_t stream) {
  const float* latents = (const float*)d_in[0];
  const float* E       = (const float*)d_in[1];
  float* out = (float*)d_out;
  char*  ws  = (char*)d_ws;
  u16*   Xb    = (u16*)(ws + WS_XB);
  u16*   Eb    = (u16*)(ws + WS_EB);
  float* norms = (float*)(ws + WS_NORM);
  int*   indsp = (int*)(ws + WS_INDS);
  float* acc   = (float*)(ws + WS_ACC);

  k_prep<<<KCODE, 256, 0, stream>>>(E, Eb, norms, acc);
  k_transpose<<<2048, 256, 0, stream>>>(latents, Xb);
  k_argmin<<<NPIX / NT, 256, 0, stream>>>(Xb, Eb, norms, indsp);
  k_gather<<<NPIX / 64, 256, 0, stream>>>(latents, E, indsp, out, acc);
  k_final<<<1, 1, 0, stream>>>(acc, out + 8388608);
}